// Round 2
// 286.263 us; speedup vs baseline: 1.0371x; 1.0371x over previous
//
#include <hip/hip_runtime.h>

#define NSEQ  9216
#define CDIM  192
#define LOG2E 1.44269504088896f

typedef _Float16 h8_t  __attribute__((ext_vector_type(8)));
typedef _Float16 h4_t  __attribute__((ext_vector_type(4)));
typedef _Float16 h2_t  __attribute__((ext_vector_type(2)));
typedef __fp16   fp16x2 __attribute__((ext_vector_type(2)));
typedef float    f4_t  __attribute__((ext_vector_type(4)));
typedef float    f16v  __attribute__((ext_vector_type(16)));
typedef unsigned u32x2 __attribute__((ext_vector_type(2)));

static __device__ inline unsigned f2u(float f) { union { float f; unsigned u; } x; x.f = f; return x.u; }
static __device__ inline float u2f(unsigned u) { union { unsigned u; float f; } x; x.u = u; return x.f; }

// pack two f32 -> two f16 in one v_cvt_pkrtz_f16_f32
static __device__ inline unsigned cvt_pk(float a, float b) {
    union { fp16x2 h; unsigned u; } x;
    x.h = __builtin_amdgcn_cvt_pkrtz(a, b);
    return x.u;
}

// v_permlane32_swap_b32: r[0] = {a.lo, b.lo-from-partner}, r[1] = {a.hi-from-partner, b.hi}
static __device__ inline u32x2 plswap(unsigned a, unsigned b) {
    return __builtin_amdgcn_permlane32_swap(a, b, false, false);
}

// ---------------------------------------------------------------------------
// Kernel 0: Wq/Wk/Wv fp32 -> f16 Wh[3][192][192].  Wq pre-scaled by log2e.
// ---------------------------------------------------------------------------
__global__ __launch_bounds__(256) void wconv_kernel(
    const float* __restrict__ Wq, const float* __restrict__ Wk,
    const float* __restrict__ Wv, _Float16* __restrict__ Wh)
{
    int i = blockIdx.x * 256 + threadIdx.x;     // f4 index, 3*9216 total
    if (i >= 3 * 9216) return;
    const float* src = (i < 9216) ? Wq : (i < 18432 ? Wk : Wv);
    float s = (i < 9216) ? LOG2E : 1.f;
    int r = i % 9216;
    f4_t w = ((const f4_t*)src)[r];
    h4_t h = {(_Float16)(w[0]*s), (_Float16)(w[1]*s),
              (_Float16)(w[2]*s), (_Float16)(w[3]*s)};
    ((h4_t*)Wh)[i] = h;
}

// ---------------------------------------------------------------------------
// Kernel 1: QKV projection via 32x32x16 MFMA (one wave per (mat, 32-seq)).
// ---------------------------------------------------------------------------
__global__ __launch_bounds__(256) void proj_kernel(
    const float* __restrict__ x, const _Float16* __restrict__ Wh,
    const float* __restrict__ bq, const float* __restrict__ bk,
    const float* __restrict__ bv,
    _Float16* __restrict__ QT, _Float16* __restrict__ KT, _Float16* __restrict__ Vg)
{
    const int tid  = threadIdx.x;
    const int lane = tid & 63, wave = tid >> 6;
    const int L31  = lane & 31, hi = lane >> 5;
    const int idx  = blockIdx.x * 4 + wave;      // 0..1727
    const int mat  = idx / 576;
    const int rem  = idx % 576;
    const int b    = rem / 288;
    const int n0   = (rem % 288) * 32;
    const int n    = n0 + L31;

    h8_t bf[12];
    #pragma unroll
    for (int t = 0; t < 12; t++) {
        h8_t h;
        #pragma unroll
        for (int j = 0; j < 8; j++)
            h[j] = (_Float16)x[(size_t)(b * CDIM + t * 16 + hi * 8 + j) * NSEQ + n];
        bf[t] = h;
    }

    const _Float16* W = Wh + mat * CDIM * CDIM;
    const float* bias = (mat == 0) ? bq : (mat == 1 ? bk : bv);
    const float bscale = (mat == 0) ? LOG2E : 1.f;

    f16v acc[6];
    #pragma unroll
    for (int s = 0; s < 6; s++)
        #pragma unroll
        for (int r = 0; r < 16; r++) acc[s][r] = 0.f;

    #pragma unroll
    for (int t = 0; t < 12; t++) {
        #pragma unroll
        for (int s = 0; s < 6; s++) {
            h8_t a = *(const h8_t*)(W + (s * 32 + L31) * CDIM + t * 16 + hi * 8);
            acc[s] = __builtin_amdgcn_mfma_f32_32x32x16_f16(a, bf[t], acc[s], 0, 0, 0);
        }
    }

    if (mat < 2) {
        _Float16* dst = ((mat == 0) ? QT : KT) + ((size_t)b * NSEQ + n) * CDIM;
        #pragma unroll
        for (int s = 0; s < 6; s++) {
            #pragma unroll
            for (int g = 0; g < 4; g++) {
                f4_t bb = *(const f4_t*)&bias[s * 32 + 8 * g + 4 * hi];
                h4_t h = {(_Float16)(acc[s][4*g+0] + bb[0] * bscale),
                          (_Float16)(acc[s][4*g+1] + bb[1] * bscale),
                          (_Float16)(acc[s][4*g+2] + bb[2] * bscale),
                          (_Float16)(acc[s][4*g+3] + bb[3] * bscale)};
                *(h4_t*)(dst + s * 32 + 8 * g + 4 * hi) = h;
            }
        }
    } else {
        #pragma unroll
        for (int s = 0; s < 6; s++) {
            #pragma unroll
            for (int g = 0; g < 4; g++) {
                f4_t bb = *(const f4_t*)&bias[s * 32 + 8 * g + 4 * hi];
                #pragma unroll
                for (int r = 0; r < 4; r++) {
                    int o = s * 32 + 8 * g + 4 * hi + r;
                    Vg[((size_t)b * CDIM + o) * NSEQ + n] =
                        (_Float16)(acc[s][4*g+r] + bb[r]);
                }
            }
        }
    }
}

// ---------------------------------------------------------------------------
// Kernel 2: flash attention.
//   KTILE=32, single K+V LDS buffer, two barriers per iter, next-tile loads
//   prefetched into registers right after the second barrier.
//   S^T = K*Q (D[m=key][n=q]); P->B-operand via permlane32_swap (no LDS, no
//   selects); PV flipped: D[m=c][n=q], V as A-op.
//   Online softmax in log2 domain with DEFER-MAX (T13): acc rescale only when
//   the tile max exceeds the running reference by >9 (P bounded by 2^9,
//   safe in f16; rescale becomes a rare event instead of every iteration).
// ---------------------------------------------------------------------------
template<int NSPLIT>
__global__ __launch_bounds__(256, 2) void flash_kernel(
    const _Float16* __restrict__ QT, const _Float16* __restrict__ KTg,
    const _Float16* __restrict__ Vg,
    _Float16* __restrict__ O_part, float* __restrict__ m_part, float* __restrict__ l_part)
{
    constexpr int KPS    = NSEQ / NSPLIT;
    constexpr int KITERS = KPS / 32;
    constexpr int KBUF   = 32 * 200;          // halfwords
    // Sh: staging (K 6400 + V 7680 = 14080 hw) and epilogue transpose
    // (4 waves x 6400 hw = 25600 hw) share the same allocation.
    __shared__ __align__(16) _Float16 Sh[25600];   // 51,200 B

    const int tid  = threadIdx.x;
    const int lane = tid & 63, wave = tid >> 6;
    const int L31  = lane & 31, hi = lane >> 5;
    const int qtile = blockIdx.x, split = blockIdx.y, b = blockIdx.z;
    const int q0 = qtile * 128 + wave * 32;

    // resident Q B-fragments: B[k=c][col=q=L31]
    h8_t qf[12];
    const _Float16* qbase = QT + ((size_t)b * NSEQ + q0 + L31) * CDIM + hi * 8;
    #pragma unroll
    for (int t = 0; t < 12; t++) qf[t] = *(const h8_t*)(qbase + t * 16);

    f16v acc[6];
    #pragma unroll
    for (int s = 0; s < 6; s++)
        #pragma unroll
        for (int r = 0; r < 16; r++) acc[s][r] = 0.f;
    float m_run = -__builtin_inff();
    float l_run = 0.f;

    const _Float16* ksrc = KTg + ((size_t)b * NSEQ + split * KPS) * CDIM;
    const _Float16* vsrc = Vg + (size_t)b * CDIM * NSEQ + split * KPS;

    // staging maps (loop-invariant): 768 h8-chunks each for K and V
    int kds[3], vds[3];
    const _Float16 *kgl[3], *vgl[3];
    #pragma unroll
    for (int r = 0; r < 3; r++) {
        int i = r * 256 + tid;
        kds[r] = (i / 24) * 200 + (i % 24) * 8;
        kgl[r] = ksrc + i * 8;
        int c = i >> 2, seg = i & 3;
        vds[r] = KBUF + c * 40 + seg * 8;
        vgl[r] = vsrc + (size_t)c * NSEQ + seg * 8;
    }

    h8_t kreg[3], vreg[3];
    #pragma unroll
    for (int r = 0; r < 3; r++) kreg[r] = *(const h8_t*)(kgl[r]);
    #pragma unroll
    for (int r = 0; r < 3; r++) vreg[r] = *(const h8_t*)(vgl[r]);

    for (int kt = 0; kt < KITERS; kt++) {
        __syncthreads();                    // prev iter's LDS reads done
        #pragma unroll
        for (int r = 0; r < 3; r++) *(h8_t*)(Sh + kds[r]) = kreg[r];
        #pragma unroll
        for (int r = 0; r < 3; r++) *(h8_t*)(Sh + vds[r]) = vreg[r];
        __syncthreads();                    // LDS tile ready
        if (kt + 1 < KITERS) {              // loads in flight through this iter
            #pragma unroll
            for (int r = 0; r < 3; r++)
                kreg[r] = *(const h8_t*)(kgl[r] + (kt + 1) * 32 * CDIM);
            #pragma unroll
            for (int r = 0; r < 3; r++)
                vreg[r] = *(const h8_t*)(vgl[r] + (kt + 1) * 32);
        }

        // S^T[key][q]: A = K[key=L31][c], B = qf
        f16v st;
        #pragma unroll
        for (int r = 0; r < 16; r++) st[r] = 0.f;
        #pragma unroll
        for (int t = 0; t < 12; t++) {
            h8_t a = *(const h8_t*)(Sh + L31 * 200 + t * 16 + hi * 8);
            st = __builtin_amdgcn_mfma_f32_32x32x16_f16(a, qf[t], st, 0, 0, 0);
        }

        // tile max (max3-friendly tree), then cross-half combine via permlane
        float a0 = fmaxf(fmaxf(st[0], st[1]),  st[2]);
        float a1 = fmaxf(fmaxf(st[3], st[4]),  st[5]);
        float a2 = fmaxf(fmaxf(st[6], st[7]),  st[8]);
        float a3 = fmaxf(fmaxf(st[9], st[10]), st[11]);
        float a4 = fmaxf(fmaxf(st[12], st[13]), st[14]);
        float mx = fmaxf(fmaxf(fmaxf(a0, a1), fmaxf(a2, a3)), fmaxf(a4, st[15]));
        u32x2 mxw = plswap(f2u(mx), f2u(mx));
        mx = fmaxf(u2f(mxw[0]), u2f(mxw[1]));

        // defer-max: rescale only on significant max growth (rare after iter 0)
        if (__builtin_expect(__any(mx > m_run + 9.f), 0)) {
            float m_new = fmaxf(m_run, mx);
            float alpha = __builtin_exp2f(m_run - m_new);   // per-lane (q=L31)
            l_run *= alpha;
            #pragma unroll
            for (int cs = 0; cs < 6; cs++)
                #pragma unroll
                for (int r = 0; r < 16; r++) acc[cs][r] *= alpha;
            m_run = m_new;
        }

        // P = exp2(S - m_run) (bounded by 2^9), pack to f16 pairs via cvt_pkrtz
        // pk[2t+e] holds keys 8t+4hi+{2e,2e+1} (key of st[r] = (r&3)+8(r>>2)+4hi)
        unsigned pu[8];
        float ps0 = 0.f, ps1 = 0.f;
        #pragma unroll
        for (int t2 = 0; t2 < 8; t2++) {
            float e0 = __builtin_exp2f(st[2*t2]   - m_run);
            float e1 = __builtin_exp2f(st[2*t2+1] - m_run);
            ps0 += e0; ps1 += e1;
            pu[t2] = cvt_pk(e0, e1);
        }
        l_run += ps0 + ps1;

        // half-exchange via permlane32_swap: both outputs are directly the
        // needed B-fragment words (no cndmask):
        //   x[0] = {own.lo, partner-of-hi}, x[1] = {partner-of-lo, own.hi}
        union { h8_t h; unsigned u[4]; } pb0, pb1;
        u32x2 x0 = plswap(pu[0], pu[2]);
        u32x2 x1 = plswap(pu[1], pu[3]);
        u32x2 x2 = plswap(pu[4], pu[6]);
        u32x2 x3 = plswap(pu[5], pu[7]);
        pb0.u[0] = x0[0]; pb0.u[1] = x1[0]; pb0.u[2] = x0[1]; pb0.u[3] = x1[1];
        pb1.u[0] = x2[0]; pb1.u[1] = x3[0]; pb1.u[2] = x2[1]; pb1.u[3] = x3[1];

        // PV flipped: D[m=c][n=q] += V[c][key] * P^T[key][q]
        #pragma unroll
        for (int ks = 0; ks < 2; ks++) {
            h8_t pb = ks ? pb1.h : pb0.h;
            #pragma unroll
            for (int cs = 0; cs < 6; cs++) {
                h8_t va = *(const h8_t*)(Sh + KBUF + (cs * 32 + L31) * 40 + ks * 16 + hi * 8);
                acc[cs] = __builtin_amdgcn_mfma_f32_32x32x16_f16(va, pb, acc[cs], 0, 0, 0);
            }
        }
    }

    // epilogue
    u32x2 lw = plswap(f2u(l_run), f2u(l_run));
    float l_tot = u2f(lw[0]) + u2f(lw[1]);
    const size_t pw = (size_t)(b * NSPLIT + split) * NSEQ + q0;
    if (lane < 32) {
        m_part[pw + lane] = m_run;
        l_part[pw + lane] = l_tot;
    }
    __syncthreads();                       // all LDS reads of Sh done
    // per-wave transpose through LDS: acc rows are c, cols are q
    _Float16* T = Sh + wave * 6400;
    #pragma unroll
    for (int cs = 0; cs < 6; cs++)
        #pragma unroll
        for (int g = 0; g < 4; g++) {
            h4_t hh = {(_Float16)acc[cs][4*g+0], (_Float16)acc[cs][4*g+1],
                       (_Float16)acc[cs][4*g+2], (_Float16)acc[cs][4*g+3]};
            // c = cs*32 + 8g + 4hi + j, row q = L31
            *(h4_t*)(T + L31 * 200 + cs * 32 + 8 * g + 4 * hi) = hh;
        }
    _Float16* ob = O_part + pw * CDIM;
    #pragma unroll
    for (int it = 0; it < 12; it++) {
        int i = it * 64 + lane;
        int qq = i / 24, col = i % 24;
        h8_t h = *(const h8_t*)(T + qq * 200 + col * 8);
        *(h8_t*)(ob + (size_t)qq * CDIM + col * 8) = h;
    }
}

// ---------------------------------------------------------------------------
// Kernel 3: merge NS splits, normalize (log2 domain), transpose to out[b][c][n]
// ---------------------------------------------------------------------------
template<int NS>
__global__ __launch_bounds__(256) void combine_kernel(
    const _Float16* __restrict__ O_part, const float* __restrict__ m_part,
    const float* __restrict__ l_part, float* __restrict__ out)
{
    __shared__ float Cs[CDIM][33];
    __shared__ float winv[NS][32];
    const int tid = threadIdx.x;
    const int b  = blockIdx.y;
    const int n0 = blockIdx.x * 32;

    if (tid < 32) {
        int n = n0 + tid;
        float mm[NS], ll[NS], ms = -__builtin_inff();
        #pragma unroll
        for (int s = 0; s < NS; s++) {
            mm[s] = m_part[(b * NS + s) * NSEQ + n];
            ll[s] = l_part[(b * NS + s) * NSEQ + n];
            ms = fmaxf(ms, mm[s]);
        }
        float denom = 0.f;
        #pragma unroll
        for (int s = 0; s < NS; s++) {
            float w = __builtin_exp2f(mm[s] - ms);
            mm[s] = w;
            denom += w * ll[s];
        }
        #pragma unroll
        for (int s = 0; s < NS; s++) winv[s][tid] = mm[s] / denom;
    }
    __syncthreads();

    for (int i = tid; i < 32 * 96; i += 256) {
        int nl = i / 96, cp = i % 96;
        float v0 = 0.f, v1 = 0.f;
        #pragma unroll
        for (int s = 0; s < NS; s++) {
            h2_t op = *(const h2_t*)(O_part +
                ((size_t)(b * NS + s) * NSEQ + n0 + nl) * CDIM + cp * 2);
            float w = winv[s][nl];
            v0 += w * (float)op[0];
            v1 += w * (float)op[1];
        }
        Cs[cp * 2][nl] = v0;
        Cs[cp * 2 + 1][nl] = v1;
    }
    __syncthreads();
    for (int i = tid; i < CDIM * 32; i += 256) {
        int nl = i & 31, c = i >> 5;
        out[((size_t)b * CDIM + c) * NSEQ + n0 + nl] = Cs[c][nl];
    }
}

// ---------------------------------------------------------------------------
extern "C" void kernel_launch(void* const* d_in, const int* in_sizes, int n_in,
                              void* d_out, int out_size, void* d_ws, size_t ws_size,
                              hipStream_t stream)
{
    const float* x  = (const float*)d_in[0];
    const float* Wq = (const float*)d_in[1];
    const float* bq = (const float*)d_in[2];
    const float* Wk = (const float*)d_in[3];
    const float* bk = (const float*)d_in[4];
    const float* Wv = (const float*)d_in[5];
    const float* bv = (const float*)d_in[6];
    float* out = (float*)d_out;

    // workspace layout
    char* ws = (char*)d_ws;
    _Float16* QT = (_Float16*)(ws);                    // 7,077,888 B
    _Float16* KT = (_Float16*)(ws + 7077888);
    _Float16* Vg = (_Float16*)(ws + 14155776);
    char* tail = ws + 21233664;
    _Float16* Wh = (_Float16*)tail;                    // 221,184 B, aliases O_part
    _Float16* O_part = (_Float16*)tail;                // NS * 7,077,888 B (f16)

    wconv_kernel<<<108, 256, 0, stream>>>(Wq, Wk, Wv, Wh);
    proj_kernel<<<432, 256, 0, stream>>>(x, Wh, bq, bk, bv, QT, KT, Vg);

    const size_t need8 = 21233664ull + 8 * 7077888ull + 2 * 589824ull;  // 79,036,416
    const size_t need4 = 21233664ull + 4 * 7077888ull + 2 * 294912ull;  // 50,135,040
    if (ws_size >= need8) {
        float* m_part = (float*)(tail + 8 * 7077888ull);
        float* l_part = (float*)(tail + 8 * 7077888ull + 589824ull);
        flash_kernel<8><<<dim3(72, 8, 2), 256, 0, stream>>>(QT, KT, Vg, O_part, m_part, l_part);
        combine_kernel<8><<<dim3(288, 2), 256, 0, stream>>>(O_part, m_part, l_part, out);
    } else if (ws_size >= need4) {
        float* m_part = (float*)(tail + 4 * 7077888ull);
        float* l_part = (float*)(tail + 4 * 7077888ull + 294912ull);
        flash_kernel<4><<<dim3(72, 4, 2), 256, 0, stream>>>(QT, KT, Vg, O_part, m_part, l_part);
        combine_kernel<4><<<dim3(288, 2), 256, 0, stream>>>(O_part, m_part, l_part, out);
    } else {
        float* m_part = (float*)(tail + 2 * 7077888ull);
        float* l_part = (float*)(tail + 2 * 7077888ull + 147456ull);
        flash_kernel<2><<<dim3(72, 2, 2), 256, 0, stream>>>(QT, KT, Vg, O_part, m_part, l_part);
        combine_kernel<2><<<dim3(288, 2), 256, 0, stream>>>(O_part, m_part, l_part, out);
    }
}

// Round 3
// 283.050 us; speedup vs baseline: 1.0488x; 1.0114x over previous
//
#include <hip/hip_runtime.h>

#define NSEQ  9216
#define CDIM  192
#define LOG2E 1.44269504088896f

typedef _Float16 h8_t  __attribute__((ext_vector_type(8)));
typedef _Float16 h4_t  __attribute__((ext_vector_type(4)));
typedef _Float16 h2_t  __attribute__((ext_vector_type(2)));
typedef __fp16   fp16x2 __attribute__((ext_vector_type(2)));
typedef float    f4_t  __attribute__((ext_vector_type(4)));
typedef float    f16v  __attribute__((ext_vector_type(16)));
typedef unsigned u32x2 __attribute__((ext_vector_type(2)));

static __device__ inline unsigned f2u(float f) { union { float f; unsigned u; } x; x.f = f; return x.u; }
static __device__ inline float u2f(unsigned u) { union { unsigned u; float f; } x; x.u = u; return x.f; }

// pack two f32 -> two f16 in one v_cvt_pkrtz_f16_f32
static __device__ inline unsigned cvt_pk(float a, float b) {
    union { fp16x2 h; unsigned u; } x;
    x.h = __builtin_amdgcn_cvt_pkrtz(a, b);
    return x.u;
}

// v_permlane32_swap_b32: r[0] = {a.lo, b.lo-from-partner}, r[1] = {a.hi-from-partner, b.hi}
static __device__ inline u32x2 plswap(unsigned a, unsigned b) {
    return __builtin_amdgcn_permlane32_swap(a, b, false, false);
}

// ---------------------------------------------------------------------------
// Kernel 0: Wq/Wk/Wv fp32 -> f16 Wh[3][192][192].  Wq pre-scaled by log2e.
// ---------------------------------------------------------------------------
__global__ __launch_bounds__(256) void wconv_kernel(
    const float* __restrict__ Wq, const float* __restrict__ Wk,
    const float* __restrict__ Wv, _Float16* __restrict__ Wh)
{
    int i = blockIdx.x * 256 + threadIdx.x;     // f4 index, 3*9216 total
    if (i >= 3 * 9216) return;
    const float* src = (i < 9216) ? Wq : (i < 18432 ? Wk : Wv);
    float s = (i < 9216) ? LOG2E : 1.f;
    int r = i % 9216;
    f4_t w = ((const f4_t*)src)[r];
    h4_t h = {(_Float16)(w[0]*s), (_Float16)(w[1]*s),
              (_Float16)(w[2]*s), (_Float16)(w[3]*s)};
    ((h4_t*)Wh)[i] = h;
}

// ---------------------------------------------------------------------------
// Kernel 1: QKV projection via 32x32x16 MFMA (one wave per (mat, 32-seq)).
// ---------------------------------------------------------------------------
__global__ __launch_bounds__(256) void proj_kernel(
    const float* __restrict__ x, const _Float16* __restrict__ Wh,
    const float* __restrict__ bq, const float* __restrict__ bk,
    const float* __restrict__ bv,
    _Float16* __restrict__ QT, _Float16* __restrict__ KT, _Float16* __restrict__ Vg)
{
    const int tid  = threadIdx.x;
    const int lane = tid & 63, wave = tid >> 6;
    const int L31  = lane & 31, hi = lane >> 5;
    const int idx  = blockIdx.x * 4 + wave;      // 0..1727
    const int mat  = idx / 576;
    const int rem  = idx % 576;
    const int b    = rem / 288;
    const int n0   = (rem % 288) * 32;
    const int n    = n0 + L31;

    h8_t bf[12];
    #pragma unroll
    for (int t = 0; t < 12; t++) {
        h8_t h;
        #pragma unroll
        for (int j = 0; j < 8; j++)
            h[j] = (_Float16)x[(size_t)(b * CDIM + t * 16 + hi * 8 + j) * NSEQ + n];
        bf[t] = h;
    }

    const _Float16* W = Wh + mat * CDIM * CDIM;
    const float* bias = (mat == 0) ? bq : (mat == 1 ? bk : bv);
    const float bscale = (mat == 0) ? LOG2E : 1.f;

    f16v acc[6];
    #pragma unroll
    for (int s = 0; s < 6; s++)
        #pragma unroll
        for (int r = 0; r < 16; r++) acc[s][r] = 0.f;

    #pragma unroll
    for (int t = 0; t < 12; t++) {
        #pragma unroll
        for (int s = 0; s < 6; s++) {
            h8_t a = *(const h8_t*)(W + (s * 32 + L31) * CDIM + t * 16 + hi * 8);
            acc[s] = __builtin_amdgcn_mfma_f32_32x32x16_f16(a, bf[t], acc[s], 0, 0, 0);
        }
    }

    if (mat < 2) {
        _Float16* dst = ((mat == 0) ? QT : KT) + ((size_t)b * NSEQ + n) * CDIM;
        #pragma unroll
        for (int s = 0; s < 6; s++) {
            #pragma unroll
            for (int g = 0; g < 4; g++) {
                f4_t bb = *(const f4_t*)&bias[s * 32 + 8 * g + 4 * hi];
                h4_t h = {(_Float16)(acc[s][4*g+0] + bb[0] * bscale),
                          (_Float16)(acc[s][4*g+1] + bb[1] * bscale),
                          (_Float16)(acc[s][4*g+2] + bb[2] * bscale),
                          (_Float16)(acc[s][4*g+3] + bb[3] * bscale)};
                *(h4_t*)(dst + s * 32 + 8 * g + 4 * hi) = h;
            }
        }
    } else {
        #pragma unroll
        for (int s = 0; s < 6; s++) {
            #pragma unroll
            for (int g = 0; g < 4; g++) {
                f4_t bb = *(const f4_t*)&bias[s * 32 + 8 * g + 4 * hi];
                #pragma unroll
                for (int r = 0; r < 4; r++) {
                    int o = s * 32 + 8 * g + 4 * hi + r;
                    Vg[((size_t)b * CDIM + o) * NSEQ + n] =
                        (_Float16)(acc[s][4*g+r] + bb[r]);
                }
            }
        }
    }
}

// ---------------------------------------------------------------------------
// Kernel 2: flash attention.
//   KTILE=32, DOUBLE-buffered K+V LDS, ONE barrier per iteration:
//     iter t: ds_write tile t+1 (regs loaded during t-1) -> buf[(t+1)&1],
//             issue global loads for tile t+2, compute from buf[t&1], barrier.
//   WAR/RAW hazards are separated by the previous iteration's barrier.
//   S^T = K*Q (D[m=key][n=q]); P->B-operand via permlane32_swap; PV flipped:
//   D[m=c][n=q], V as A-op.  Online softmax in log2 domain with DEFER-MAX:
//   acc rescale only when tile max exceeds running ref by >9.
// ---------------------------------------------------------------------------
template<int NSPLIT>
__global__ __launch_bounds__(256, 2) void flash_kernel(
    const _Float16* __restrict__ QT, const _Float16* __restrict__ KTg,
    const _Float16* __restrict__ Vg,
    _Float16* __restrict__ O_part, float* __restrict__ m_part, float* __restrict__ l_part)
{
    constexpr int KPS    = NSEQ / NSPLIT;
    constexpr int KITERS = KPS / 32;
    constexpr int KBUF   = 32 * 200;          // K halfwords per tile (6400)
    constexpr int DBUF   = 14080;             // halfwords per buffer (K 6400 + V 7680)
    // Sh: double-buffered staging (2 x 14080 hw) and epilogue transpose
    // (4 waves x 6400 hw = 25600 hw) share the same allocation.
    __shared__ __align__(16) _Float16 Sh[2 * DBUF];   // 56,320 B

    const int tid  = threadIdx.x;
    const int lane = tid & 63, wave = tid >> 6;
    const int L31  = lane & 31, hi = lane >> 5;
    const int qtile = blockIdx.x, split = blockIdx.y, b = blockIdx.z;
    const int q0 = qtile * 128 + wave * 32;

    // resident Q B-fragments: B[k=c][col=q=L31]
    h8_t qf[12];
    const _Float16* qbase = QT + ((size_t)b * NSEQ + q0 + L31) * CDIM + hi * 8;
    #pragma unroll
    for (int t = 0; t < 12; t++) qf[t] = *(const h8_t*)(qbase + t * 16);

    f16v acc[6];
    #pragma unroll
    for (int s = 0; s < 6; s++)
        #pragma unroll
        for (int r = 0; r < 16; r++) acc[s][r] = 0.f;
    float m_run = -__builtin_inff();
    float l_run = 0.f;

    const _Float16* ksrc = KTg + ((size_t)b * NSEQ + split * KPS) * CDIM;
    const _Float16* vsrc = Vg + (size_t)b * CDIM * NSEQ + split * KPS;

    // staging maps (loop-invariant): 768 h8-chunks each for K and V
    int kds[3], vds[3];
    const _Float16 *kgl[3], *vgl[3];
    #pragma unroll
    for (int r = 0; r < 3; r++) {
        int i = r * 256 + tid;
        kds[r] = (i / 24) * 200 + (i % 24) * 8;
        kgl[r] = ksrc + i * 8;
        int c = i >> 2, seg = i & 3;
        vds[r] = KBUF + c * 40 + seg * 8;
        vgl[r] = vsrc + (size_t)c * NSEQ + seg * 8;
    }

    h8_t kreg[3], vreg[3];
    // prologue: tile 0 -> buf0; tile 1 loads left in flight
    #pragma unroll
    for (int r = 0; r < 3; r++) kreg[r] = *(const h8_t*)(kgl[r]);
    #pragma unroll
    for (int r = 0; r < 3; r++) vreg[r] = *(const h8_t*)(vgl[r]);
    #pragma unroll
    for (int r = 0; r < 3; r++) *(h8_t*)(Sh + kds[r]) = kreg[r];
    #pragma unroll
    for (int r = 0; r < 3; r++) *(h8_t*)(Sh + vds[r]) = vreg[r];
    if (KITERS > 1) {
        #pragma unroll
        for (int r = 0; r < 3; r++) kreg[r] = *(const h8_t*)(kgl[r] + 32 * CDIM);
        #pragma unroll
        for (int r = 0; r < 3; r++) vreg[r] = *(const h8_t*)(vgl[r] + 32);
    }
    __syncthreads();

    for (int kt = 0; kt < KITERS; kt++) {
        const int rb = (kt & 1) * DBUF;
        const int wb = ((kt + 1) & 1) * DBUF;

        // stage tile kt+1 (regs landed during iter kt-1's compute)
        if (kt + 1 < KITERS) {
            #pragma unroll
            for (int r = 0; r < 3; r++) *(h8_t*)(Sh + wb + kds[r]) = kreg[r];
            #pragma unroll
            for (int r = 0; r < 3; r++) *(h8_t*)(Sh + wb + vds[r]) = vreg[r];
        }
        // issue loads for tile kt+2 (land during this compute + next iter)
        if (kt + 2 < KITERS) {
            #pragma unroll
            for (int r = 0; r < 3; r++)
                kreg[r] = *(const h8_t*)(kgl[r] + (kt + 2) * 32 * CDIM);
            #pragma unroll
            for (int r = 0; r < 3; r++)
                vreg[r] = *(const h8_t*)(vgl[r] + (kt + 2) * 32);
        }

        // S^T[key][q]: A = K[key=L31][c], B = qf
        f16v st;
        #pragma unroll
        for (int r = 0; r < 16; r++) st[r] = 0.f;
        #pragma unroll
        for (int t = 0; t < 12; t++) {
            h8_t a = *(const h8_t*)(Sh + rb + L31 * 200 + t * 16 + hi * 8);
            st = __builtin_amdgcn_mfma_f32_32x32x16_f16(a, qf[t], st, 0, 0, 0);
        }

        // tile max (max3-friendly tree), then cross-half combine via permlane
        float a0 = fmaxf(fmaxf(st[0], st[1]),  st[2]);
        float a1 = fmaxf(fmaxf(st[3], st[4]),  st[5]);
        float a2 = fmaxf(fmaxf(st[6], st[7]),  st[8]);
        float a3 = fmaxf(fmaxf(st[9], st[10]), st[11]);
        float a4 = fmaxf(fmaxf(st[12], st[13]), st[14]);
        float mx = fmaxf(fmaxf(fmaxf(a0, a1), fmaxf(a2, a3)), fmaxf(a4, st[15]));
        u32x2 mxw = plswap(f2u(mx), f2u(mx));
        mx = fmaxf(u2f(mxw[0]), u2f(mxw[1]));

        // defer-max: rescale only on significant max growth (rare after iter 0)
        if (__builtin_expect(__any(mx > m_run + 9.f), 0)) {
            float m_new = fmaxf(m_run, mx);
            float alpha = __builtin_exp2f(m_run - m_new);   // per-lane (q=L31)
            l_run *= alpha;
            #pragma unroll
            for (int cs = 0; cs < 6; cs++)
                #pragma unroll
                for (int r = 0; r < 16; r++) acc[cs][r] *= alpha;
            m_run = m_new;
        }

        // P = exp2(S - m_run) (bounded by 2^9), pack to f16 pairs via cvt_pkrtz
        // pk[2t+e] holds keys 8t+4hi+{2e,2e+1} (key of st[r] = (r&3)+8(r>>2)+4hi)
        unsigned pu[8];
        float ps0 = 0.f, ps1 = 0.f;
        #pragma unroll
        for (int t2 = 0; t2 < 8; t2++) {
            float e0 = __builtin_exp2f(st[2*t2]   - m_run);
            float e1 = __builtin_exp2f(st[2*t2+1] - m_run);
            ps0 += e0; ps1 += e1;
            pu[t2] = cvt_pk(e0, e1);
        }
        l_run += ps0 + ps1;

        // half-exchange via permlane32_swap: both outputs are directly the
        // needed B-fragment words (no cndmask):
        //   x[0] = {own.lo, partner-of-hi}, x[1] = {partner-of-lo, own.hi}
        union { h8_t h; unsigned u[4]; } pb0, pb1;
        u32x2 x0 = plswap(pu[0], pu[2]);
        u32x2 x1 = plswap(pu[1], pu[3]);
        u32x2 x2 = plswap(pu[4], pu[6]);
        u32x2 x3 = plswap(pu[5], pu[7]);
        pb0.u[0] = x0[0]; pb0.u[1] = x1[0]; pb0.u[2] = x0[1]; pb0.u[3] = x1[1];
        pb1.u[0] = x2[0]; pb1.u[1] = x3[0]; pb1.u[2] = x2[1]; pb1.u[3] = x3[1];

        // PV flipped: D[m=c][n=q] += V[c][key] * P^T[key][q]
        #pragma unroll
        for (int ks = 0; ks < 2; ks++) {
            h8_t pb = ks ? pb1.h : pb0.h;
            #pragma unroll
            for (int cs = 0; cs < 6; cs++) {
                h8_t va = *(const h8_t*)(Sh + rb + KBUF + (cs * 32 + L31) * 40 + ks * 16 + hi * 8);
                acc[cs] = __builtin_amdgcn_mfma_f32_32x32x16_f16(va, pb, acc[cs], 0, 0, 0);
            }
        }

        __syncthreads();   // single convergence point per tile
    }

    // epilogue
    u32x2 lw = plswap(f2u(l_run), f2u(l_run));
    float l_tot = u2f(lw[0]) + u2f(lw[1]);
    const size_t pw = (size_t)(b * NSPLIT + split) * NSEQ + q0;
    if (lane < 32) {
        m_part[pw + lane] = m_run;
        l_part[pw + lane] = l_tot;
    }
    // loop-end barrier already separates last tile's LDS reads from reuse
    // per-wave transpose through LDS: acc rows are c, cols are q
    _Float16* T = Sh + wave * 6400;
    #pragma unroll
    for (int cs = 0; cs < 6; cs++)
        #pragma unroll
        for (int g = 0; g < 4; g++) {
            h4_t hh = {(_Float16)acc[cs][4*g+0], (_Float16)acc[cs][4*g+1],
                       (_Float16)acc[cs][4*g+2], (_Float16)acc[cs][4*g+3]};
            // c = cs*32 + 8g + 4hi + j, row q = L31
            *(h4_t*)(T + L31 * 200 + cs * 32 + 8 * g + 4 * hi) = hh;
        }
    _Float16* ob = O_part + pw * CDIM;
    #pragma unroll
    for (int it = 0; it < 12; it++) {
        int i = it * 64 + lane;
        int qq = i / 24, col = i % 24;
        h8_t h = *(const h8_t*)(T + qq * 200 + col * 8);
        *(h8_t*)(ob + (size_t)qq * CDIM + col * 8) = h;
    }
}

// ---------------------------------------------------------------------------
// Kernel 3: merge NS splits, normalize (log2 domain), transpose to out[b][c][n]
// ---------------------------------------------------------------------------
template<int NS>
__global__ __launch_bounds__(256) void combine_kernel(
    const _Float16* __restrict__ O_part, const float* __restrict__ m_part,
    const float* __restrict__ l_part, float* __restrict__ out)
{
    __shared__ float Cs[CDIM][33];
    __shared__ float winv[NS][32];
    const int tid = threadIdx.x;
    const int b  = blockIdx.y;
    const int n0 = blockIdx.x * 32;

    if (tid < 32) {
        int n = n0 + tid;
        float mm[NS], ll[NS], ms = -__builtin_inff();
        #pragma unroll
        for (int s = 0; s < NS; s++) {
            mm[s] = m_part[(b * NS + s) * NSEQ + n];
            ll[s] = l_part[(b * NS + s) * NSEQ + n];
            ms = fmaxf(ms, mm[s]);
        }
        float denom = 0.f;
        #pragma unroll
        for (int s = 0; s < NS; s++) {
            float w = __builtin_exp2f(mm[s] - ms);
            mm[s] = w;
            denom += w * ll[s];
        }
        #pragma unroll
        for (int s = 0; s < NS; s++) winv[s][tid] = mm[s] / denom;
    }
    __syncthreads();

    for (int i = tid; i < 32 * 96; i += 256) {
        int nl = i / 96, cp = i % 96;
        float v0 = 0.f, v1 = 0.f;
        #pragma unroll
        for (int s = 0; s < NS; s++) {
            h2_t op = *(const h2_t*)(O_part +
                ((size_t)(b * NS + s) * NSEQ + n0 + nl) * CDIM + cp * 2);
            float w = winv[s][nl];
            v0 += w * (float)op[0];
            v1 += w * (float)op[1];
        }
        Cs[cp * 2][nl] = v0;
        Cs[cp * 2 + 1][nl] = v1;
    }
    __syncthreads();
    for (int i = tid; i < CDIM * 32; i += 256) {
        int nl = i & 31, c = i >> 5;
        out[((size_t)b * CDIM + c) * NSEQ + n0 + nl] = Cs[c][nl];
    }
}

// ---------------------------------------------------------------------------
extern "C" void kernel_launch(void* const* d_in, const int* in_sizes, int n_in,
                              void* d_out, int out_size, void* d_ws, size_t ws_size,
                              hipStream_t stream)
{
    const float* x  = (const float*)d_in[0];
    const float* Wq = (const float*)d_in[1];
    const float* bq = (const float*)d_in[2];
    const float* Wk = (const float*)d_in[3];
    const float* bk = (const float*)d_in[4];
    const float* Wv = (const float*)d_in[5];
    const float* bv = (const float*)d_in[6];
    float* out = (float*)d_out;

    // workspace layout
    char* ws = (char*)d_ws;
    _Float16* QT = (_Float16*)(ws);                    // 7,077,888 B
    _Float16* KT = (_Float16*)(ws + 7077888);
    _Float16* Vg = (_Float16*)(ws + 14155776);
    char* tail = ws + 21233664;
    _Float16* Wh = (_Float16*)tail;                    // 221,184 B, aliases O_part
    _Float16* O_part = (_Float16*)tail;                // NS * 7,077,888 B (f16)

    wconv_kernel<<<108, 256, 0, stream>>>(Wq, Wk, Wv, Wh);
    proj_kernel<<<432, 256, 0, stream>>>(x, Wh, bq, bk, bv, QT, KT, Vg);

    const size_t need8 = 21233664ull + 8 * 7077888ull + 2 * 589824ull;  // 79,036,416
    const size_t need4 = 21233664ull + 4 * 7077888ull + 2 * 294912ull;  // 50,135,040
    if (ws_size >= need8) {
        float* m_part = (float*)(tail + 8 * 7077888ull);
        float* l_part = (float*)(tail + 8 * 7077888ull + 589824ull);
        flash_kernel<8><<<dim3(72, 8, 2), 256, 0, stream>>>(QT, KT, Vg, O_part, m_part, l_part);
        combine_kernel<8><<<dim3(288, 2), 256, 0, stream>>>(O_part, m_part, l_part, out);
    } else if (ws_size >= need4) {
        float* m_part = (float*)(tail + 4 * 7077888ull);
        float* l_part = (float*)(tail + 4 * 7077888ull + 294912ull);
        flash_kernel<4><<<dim3(72, 4, 2), 256, 0, stream>>>(QT, KT, Vg, O_part, m_part, l_part);
        combine_kernel<4><<<dim3(288, 2), 256, 0, stream>>>(O_part, m_part, l_part, out);
    } else {
        float* m_part = (float*)(tail + 2 * 7077888ull);
        float* l_part = (float*)(tail + 2 * 7077888ull + 147456ull);
        flash_kernel<2><<<dim3(72, 2, 2), 256, 0, stream>>>(QT, KT, Vg, O_part, m_part, l_part);
        combine_kernel<2><<<dim3(288, 2), 256, 0, stream>>>(O_part, m_part, l_part, out);
    }
}